// Round 3
// baseline (222.332 us; speedup 1.0000x reference)
//
#include <hip/hip_runtime.h>

#define NN 50000
#define TOPK 32
#define IN_C 128
#define OUT_C 64
#define NEG_SLOPE 0.2f
#define BN_EPS 1e-5f

// K1: 16 nodes per block, 3125 blocks (exact). 4 waves split channels
// (16 each); within a wave lane = nl*4+p: nl = node (16), p = K-quarter
// interleaved at float4 granularity.
#define K1_BLOCKS (NN / 16)       // 3125

// K2: 4 nodes per wave (16 lanes each), grid-stride
#define K2_BLOCKS 2048
#define K2_WAVES (K2_BLOCKS * 4)
#define NTASK (NN / 4)            // 12500

// workspace layout (floats)
#define WS_XBF   0                       // bf16 x_lin: NN*64*2B = NN*32 floats
#define WS_AI    (NN * 32)
#define WS_AJ    (WS_AI + NN)
#define WS_SUMS  (WS_AJ + NN)            // 128
#define WS_STATS (WS_SUMS + 128)         // 128

__device__ inline float leaky(float a) { return a >= 0.f ? a : NEG_SLOPE * a; }

__device__ inline unsigned short f2bf(float f) {     // RNE fp32 -> bf16
    unsigned u = __float_as_uint(f);
    unsigned r = (u + 0x7fffu + ((u >> 16) & 1u)) >> 16;
    return (unsigned short)r;
}
__device__ inline unsigned pack2(float lo, float hi) {
    return (unsigned)f2bf(lo) | ((unsigned)f2bf(hi) << 16);
}

// K1: x_lin(bf16) = x @ lin_w^T, plus a_i/a_j attention coefficients.
// Every x-load instruction: 16 rows x 64 contiguous bytes (16 lines, no
// 64-line scatter). Weights from LDS broadcast (4 distinct addrs on 4
// distinct bank quads = conflict-free).
__global__ __launch_bounds__(256) void k1_linear(
    const float* __restrict__ x, const float* __restrict__ emb,
    const float* __restrict__ lin_w,
    const float* __restrict__ att_i, const float* __restrict__ att_j,
    const float* __restrict__ att_em_i, const float* __restrict__ att_em_j,
    uint4* __restrict__ x_bf, float* __restrict__ a_i, float* __restrict__ a_j)
{
    __shared__ float4 wt4[IN_C / 4 * OUT_C];   // 2048 f4 = 32 KB, [c][k4]
    __shared__ float2 vs[16][4];
    const int tid = threadIdx.x;
    const float4* wg = (const float4*)lin_w;
#pragma unroll
    for (int i = 0; i < 8; ++i) wt4[tid + i * 256] = wg[tid + i * 256];
    __syncthreads();

    const int lane = tid & 63;
    const int w = tid >> 6;        // channel quarter: c in [w*16, w*16+16)
    const int nl = lane >> 2;      // node within block
    const int p = lane & 3;        // K sub-split (f4-interleaved)
    const int n = blockIdx.x * 16 + nl;

    const float4* x4 = (const float4*)x;       // row = 32 f4
    float acc[16];
#pragma unroll
    for (int c = 0; c < 16; ++c) acc[c] = 0.f;

#pragma unroll
    for (int i = 0; i < 8; ++i) {
        const float4 xk = x4[n * 32 + i * 4 + p];
#pragma unroll
        for (int c = 0; c < 16; ++c) {
            const float4 wv = wt4[(w * 16 + c) * 32 + i * 4 + p];
            acc[c] = fmaf(xk.x, wv.x, acc[c]);
            acc[c] = fmaf(xk.y, wv.y, acc[c]);
            acc[c] = fmaf(xk.z, wv.z, acc[c]);
            acc[c] = fmaf(xk.w, wv.w, acc[c]);
        }
    }
    // reduce over p (all 4 lanes of a node end with the full sums)
#pragma unroll
    for (int c = 0; c < 16; ++c) {
        acc[c] += __shfl_xor(acc[c], 1, 64);
        acc[c] += __shfl_xor(acc[c], 2, 64);
    }

    // bf16 store: p<2 each write 8 channels (16 B)
    if (p < 2) {
        uint4 pk;
        pk.x = pack2(p ? acc[8]  : acc[0], p ? acc[9]  : acc[1]);
        pk.y = pack2(p ? acc[10] : acc[2], p ? acc[11] : acc[3]);
        pk.z = pack2(p ? acc[12] : acc[4], p ? acc[13] : acc[5]);
        pk.w = pack2(p ? acc[14] : acc[6], p ? acc[15] : acc[7]);
        x_bf[n * 8 + w * 2 + p] = pk;          // row = 128 B = 8 uint4
    }

    // attention coefficients: p-lane handles channels c = w*16 + p*4 + j
    const float4 e4   = ((const float4*)emb)[n * 16 + w * 4 + p];
    const float4 ai4  = ((const float4*)att_i)[w * 4 + p];
    const float4 aj4  = ((const float4*)att_j)[w * 4 + p];
    const float4 aei4 = ((const float4*)att_em_i)[w * 4 + p];
    const float4 aej4 = ((const float4*)att_em_j)[w * 4 + p];

    float sel[4];
#pragma unroll
    for (int j = 0; j < 4; ++j) {
        const float u = (p & 1) ? acc[4 + j] : acc[j];
        const float v = (p & 1) ? acc[12 + j] : acc[8 + j];
        sel[j] = (p & 2) ? v : u;              // = acc[p*4 + j]
    }
    float vi = sel[0] * ai4.x + e4.x * aei4.x;
    float vj = sel[0] * aj4.x + e4.x * aej4.x;
    vi += sel[1] * ai4.y + e4.y * aei4.y;  vj += sel[1] * aj4.y + e4.y * aej4.y;
    vi += sel[2] * ai4.z + e4.z * aei4.z;  vj += sel[2] * aj4.z + e4.z * aej4.z;
    vi += sel[3] * ai4.w + e4.w * aei4.w;  vj += sel[3] * aj4.w + e4.w * aej4.w;
    vi += __shfl_xor(vi, 1, 64); vi += __shfl_xor(vi, 2, 64);
    vj += __shfl_xor(vj, 1, 64); vj += __shfl_xor(vj, 2, 64);
    if (p == 0) vs[nl][w] = make_float2(vi, vj);
    __syncthreads();
    if (tid < 16) {
        const float si = vs[tid][0].x + vs[tid][1].x + vs[tid][2].x + vs[tid][3].x;
        const float sj = vs[tid][0].y + vs[tid][1].y + vs[tid][2].y + vs[tid][3].y;
        a_i[blockIdx.x * 16 + tid] = si;
        a_j[blockIdx.x * 16 + tid] = sj;
    }
}

// K2: 4 nodes per wave; lane = (g = lane>>4 node, q = lane&15). Each lane
// owns 4 channels. x_lin gathered as bf16 (dwordx2 = 4 nodes x 128 B = 4
// lines per instruction), fp32 accumulate.
__global__ __launch_bounds__(256) void k2_attn(
    const int* __restrict__ src,
    const uint2* __restrict__ x_bf, const float* __restrict__ a_i,
    const float* __restrict__ a_j, const float* __restrict__ bias,
    float* __restrict__ out, float* __restrict__ sums)
{
    const int tid = threadIdx.x;
    const int lane = tid & 63;
    const int gwave = blockIdx.x * 4 + (tid >> 6);
    const int g = lane >> 4;
    const int q = lane & 15;
    const int gb = lane & 48;
    const float4 bias4 = ((const float4*)bias)[q];

    float4 bn1 = {0.f, 0.f, 0.f, 0.f}, bn2 = {0.f, 0.f, 0.f, 0.f};

    for (int task = gwave; task < NTASK; task += K2_WAVES) {
        const int t = task * 4 + g;
        const float ai_t = a_i[t];
        const float sal = leaky(ai_t + a_j[t]);            // self edge
        const int s0 = src[t * TOPK + q];
        const int s1 = src[t * TOPK + 16 + q];
        const float al0 = leaky(ai_t + a_j[s0]);
        const float al1 = leaky(ai_t + a_j[s1]);

        float m = fmaxf(al0, al1);
#pragma unroll
        for (int d = 1; d < 16; d <<= 1) m = fmaxf(m, __shfl_xor(m, d, 64));
        m = fmaxf(m, sal);
        const float e0 = __expf(al0 - m);
        const float e1 = __expf(al1 - m);
        const float es = __expf(sal - m);
        float den = e0 + e1;
#pragma unroll
        for (int d = 1; d < 16; d <<= 1) den += __shfl_xor(den, d, 64);
        den += es + 1e-16f;
        const float inv = 1.f / den;
        const float w0 = e0 * inv, w1 = e1 * inv, wself = es * inv;

        float4 A0 = {0.f,0.f,0.f,0.f}, A1 = {0.f,0.f,0.f,0.f};
        float4 A2 = {0.f,0.f,0.f,0.f}, A3 = {0.f,0.f,0.f,0.f};

#define GATHER(ACC, WE, SE)                                                   \
        {                                                                     \
            const uint2 u = x_bf[(SE) * 16 + q];                              \
            ACC.x = fmaf(WE, __uint_as_float(u.x << 16), ACC.x);              \
            ACC.y = fmaf(WE, __uint_as_float(u.x & 0xffff0000u), ACC.y);      \
            ACC.z = fmaf(WE, __uint_as_float(u.y << 16), ACC.z);              \
            ACC.w = fmaf(WE, __uint_as_float(u.y & 0xffff0000u), ACC.w);      \
        }

#pragma unroll
        for (int e = 0; e < 16; e += 4) {
            const float we0 = __shfl(w0, gb + e, 64);     const int se0 = __shfl(s0, gb + e, 64);
            const float we1 = __shfl(w0, gb + e + 1, 64); const int se1 = __shfl(s0, gb + e + 1, 64);
            const float we2 = __shfl(w0, gb + e + 2, 64); const int se2 = __shfl(s0, gb + e + 2, 64);
            const float we3 = __shfl(w0, gb + e + 3, 64); const int se3 = __shfl(s0, gb + e + 3, 64);
            GATHER(A0, we0, se0); GATHER(A1, we1, se1);
            GATHER(A2, we2, se2); GATHER(A3, we3, se3);
        }
#pragma unroll
        for (int e = 0; e < 16; e += 4) {
            const float we0 = __shfl(w1, gb + e, 64);     const int se0 = __shfl(s1, gb + e, 64);
            const float we1 = __shfl(w1, gb + e + 1, 64); const int se1 = __shfl(s1, gb + e + 1, 64);
            const float we2 = __shfl(w1, gb + e + 2, 64); const int se2 = __shfl(s1, gb + e + 2, 64);
            const float we3 = __shfl(w1, gb + e + 3, 64); const int se3 = __shfl(s1, gb + e + 3, 64);
            GATHER(A0, we0, se0); GATHER(A1, we1, se1);
            GATHER(A2, we2, se2); GATHER(A3, we3, se3);
        }
        GATHER(A0, wself, t);                   // self loop
#undef GATHER

        float4 v;
        v.x = (A0.x + A1.x) + (A2.x + A3.x) + bias4.x;
        v.y = (A0.y + A1.y) + (A2.y + A3.y) + bias4.y;
        v.z = (A0.z + A1.z) + (A2.z + A3.z) + bias4.z;
        v.w = (A0.w + A1.w) + (A2.w + A3.w) + bias4.w;
        ((float4*)out)[t * 16 + q] = v;
        bn1.x += v.x; bn1.y += v.y; bn1.z += v.z; bn1.w += v.w;
        bn2.x = fmaf(v.x, v.x, bn2.x); bn2.y = fmaf(v.y, v.y, bn2.y);
        bn2.z = fmaf(v.z, v.z, bn2.z); bn2.w = fmaf(v.w, v.w, bn2.w);
    }

    __shared__ float s1buf[64][17];
    __shared__ float s2buf[64][17];
    const int slot = tid >> 4;
    s1buf[q * 4 + 0][slot] = bn1.x; s1buf[q * 4 + 1][slot] = bn1.y;
    s1buf[q * 4 + 2][slot] = bn1.z; s1buf[q * 4 + 3][slot] = bn1.w;
    s2buf[q * 4 + 0][slot] = bn2.x; s2buf[q * 4 + 1][slot] = bn2.y;
    s2buf[q * 4 + 2][slot] = bn2.z; s2buf[q * 4 + 3][slot] = bn2.w;
    __syncthreads();
    if (tid < 64) {
        float t1 = 0.f, t2 = 0.f;
#pragma unroll
        for (int r = 0; r < 16; ++r) { t1 += s1buf[tid][r]; t2 += s2buf[tid][r]; }
        atomicAdd(&sums[tid], t1);
        atomicAdd(&sums[64 + tid], t2);
    }
}

__global__ __launch_bounds__(64) void k3_stats(
    const float* __restrict__ sums, const float* __restrict__ gamma,
    const float* __restrict__ beta, float* __restrict__ stats)
{
    const int c = threadIdx.x;
    const float mu = sums[c] / (float)NN;
    const float ex2 = sums[64 + c] / (float)NN;
    const float var = fmaxf(ex2 - mu * mu, 0.f);
    const float sc = gamma[c] / sqrtf(var + BN_EPS);
    stats[c] = sc;
    stats[64 + c] = beta[c] - mu * sc;
}

__global__ __launch_bounds__(256) void k4_bn(
    float* __restrict__ out, const float* __restrict__ stats)
{
    __shared__ float s_sc[64], s_sh[64];
    const int tid = threadIdx.x;
    if (tid < 64) { s_sc[tid] = stats[tid]; s_sh[tid] = stats[64 + tid]; }
    __syncthreads();
    const size_t total = (size_t)NN * OUT_C / 4;
    float4* p = (float4*)out;
    for (size_t idx = (size_t)blockIdx.x * 256 + tid; idx < total;
         idx += (size_t)gridDim.x * 256) {
        float4 v = p[idx];
        const int c0 = (int)((idx * 4) & 63);
        v.x = fmaxf(fmaf(v.x, s_sc[c0 + 0], s_sh[c0 + 0]), 0.f);
        v.y = fmaxf(fmaf(v.y, s_sc[c0 + 1], s_sh[c0 + 1]), 0.f);
        v.z = fmaxf(fmaf(v.z, s_sc[c0 + 2], s_sh[c0 + 2]), 0.f);
        v.w = fmaxf(fmaf(v.w, s_sc[c0 + 3], s_sh[c0 + 3]), 0.f);
        p[idx] = v;
    }
}

extern "C" void kernel_launch(void* const* d_in, const int* in_sizes, int n_in,
                              void* d_out, int out_size, void* d_ws, size_t ws_size,
                              hipStream_t stream) {
    const float* x        = (const float*)d_in[0];
    const float* emb      = (const float*)d_in[1];
    const int*   edge     = (const int*)d_in[2];   // row 0 = src
    const float* lin_w    = (const float*)d_in[3];
    const float* att_i    = (const float*)d_in[4];
    const float* att_j    = (const float*)d_in[5];
    const float* att_em_i = (const float*)d_in[6];
    const float* att_em_j = (const float*)d_in[7];
    const float* bias     = (const float*)d_in[8];
    const float* gamma    = (const float*)d_in[9];
    const float* beta     = (const float*)d_in[10];

    float* ws    = (float*)d_ws;
    uint4* x_bf  = (uint4*)(ws + WS_XBF);
    float* a_i   = ws + WS_AI;
    float* a_j   = ws + WS_AJ;
    float* sums  = ws + WS_SUMS;
    float* stats = ws + WS_STATS;
    float* out   = (float*)d_out;

    hipMemsetAsync(sums, 0, 128 * sizeof(float), stream);

    k1_linear<<<K1_BLOCKS, 256, 0, stream>>>(x, emb, lin_w, att_i, att_j,
                                             att_em_i, att_em_j, x_bf, a_i, a_j);
    k2_attn<<<K2_BLOCKS, 256, 0, stream>>>(edge, (const uint2*)x_bf, a_i, a_j,
                                           bias, out, sums);
    k3_stats<<<1, 64, 0, stream>>>(sums, gamma, beta, stats);
    k4_bn<<<3125, 256, 0, stream>>>(out, stats);
}